// Round 12
// baseline (26.604 us; speedup 1.0000x reference)
//
#include <hip/hip_runtime.h>
#include <hip/hip_bf16.h>

#define B_SZ 4096
#define IN_D 256
#define OUT_D 256
#define NC 8

#define BM 128
#define BN 32
#define SSTEPS 16           // per wave: K-slice = 64 i's = 16 steps x 4 i
#define TS 132              // tpanel stride (floats) per i  -> 132 KB LDS

using f32x4 = __attribute__((ext_vector_type(4))) float;
using s16x8 = __attribute__((ext_vector_type(8))) short;

__device__ __forceinline__ float fast_tanh(float x) {
    float e = __expf(2.0f * x);   // saturates correctly at +-inf
    return 1.0f - 2.0f / (e + 1.0f);
}

__device__ __forceinline__ unsigned int pack2(float a, float b) {
    __hip_bfloat162 h = __float22bfloat162_rn(make_float2(a, b));
    return *(unsigned int*)&h;
}

// ---------------------------------------------------------------------------
// Single-node fused KAN layer.
// Math: out[b,o] = (1/256) * sum_i [ rs[i]*t + ss[i,o]*sum_c P_c(t)*cf[i,o,c] ]
//     = sum_{i,c} bf16(P_c(t[b,i])) * W'[i,o,c],   t = tanh(x)
//   W'[i,o,c] = ss[i,o]*cf[i,o,c]/256 + (c==1 ? rs[i]/(256*(alpha+1)) : 0)
//   (P_1 = (alpha+1)*t exactly, so the residual folds into c=1.)
// Block: 128x32 output tile, 512 threads = 8 waves = 2 m-halves x 4 K-groups.
// Phase 1: tanh(x) panel (128 rows x 256 i, f32) -> LDS, fragment-interleaved.
// Phase 2: barrier-free MFMA loop; A = P_c recurrence in-register from LDS t;
//          B = W' computed in-register from global coefs (L2-resident).
// Phase 3: K-split reduction in LDS (reuses the t-panel region), store.
// ---------------------------------------------------------------------------
__global__ __launch_bounds__(512) void kan_one(
    const float* __restrict__ x, const float* __restrict__ coefs,
    const float* __restrict__ alpha_at, const float* __restrict__ resid_scale,
    const float* __restrict__ spline_scale, float* __restrict__ out)
{
    __shared__ __align__(16) float smem[IN_D * TS];   // 132 KB

    const int tid  = threadIdx.x;
    const int lane = tid & 63;
    const int wid  = tid >> 6;      // 0..7
    const int mh   = wid >> 2;      // m-half 0/1
    const int kg   = wid & 3;       // K-group 0..3 (i in [kg*64, kg*64+64))
    const int lr   = lane & 15;
    const int il   = lane >> 4;     // 0..3

    // XCD-aware bijective swizzle (256 % 8 == 0); 32 mblk x 8 nblk
    const int bid  = blockIdx.x;
    const int swz  = (bid & 7) * 32 + (bid >> 3);
    const int mblk = swz >> 3, nblk = swz & 7;
    const int bm = mblk * BM, bn = nblk * BN;

    // alpha-derived wave-uniform constants
    const float al = tanhf(alpha_at[0]);
    const float h  = al + 1.0f;
    float bc[8], cc[8];
    bc[0] = bc[1] = cc[0] = cc[1] = 0.f;
    #pragma unroll
    for (int n = 2; n < 8; n++) {
        float fn = (float)n;
        float c  = 2.f * fn + 2.f * al;
        float An = 2.f * fn * (fn + 2.f * al) * (c - 2.f);
        bc[n] = (c - 1.f) * c * (c - 2.f) / An;
        cc[n] = 2.f * (fn + al - 1.f) * (fn + al - 1.f) * c / An;
    }
    const float inv256 = 1.0f / 256.0f;
    const float r1 = inv256 / h;

    // ---- Phase 1: tanh panel -> LDS -----------------------------------
    // thread: i = tid&255, rows rb..rb+63 (rb = (tid>>8)*64). Coalesced x reads.
    // word(i, m) = i*TS + (m>>6)*64 + (m&15)*4 + ((m>>4)&3)
    {
        const int i  = tid & 255;
        const int rb = (tid >> 8) * 64;
        const float* xp = x + (size_t)(bm + rb) * IN_D + i;
        float* wp = smem + i * TS + rb;   // rb is 0 or 64 = (m>>6)*64
        #pragma unroll 8
        for (int k = 0; k < 64; k++) {
            float t = fast_tanh(xp[(size_t)k * IN_D]);
            wp[(k & 15) * 4 + (k >> 4)] = t;
        }
    }
    __syncthreads();

    // ---- Phase 2: main loop --------------------------------------------
    f32x4 acc[4][2];
    #pragma unroll
    for (int f = 0; f < 4; f++)
        #pragma unroll
        for (int g = 0; g < 2; g++)
            acc[f][g] = (f32x4){0.f, 0.f, 0.f, 0.f};

    const float* tb = smem + mh * 64 + lr * 4;

    #pragma unroll
    for (int s = 0; s < SSTEPS; ++s) {
        const int i = kg * 64 + s * 4 + il;   // this lane's feature index

        // W' fragments in-register (coalesced coef loads, L2-resident)
        const float* cp0 = coefs + ((size_t)i * OUT_D + bn + lr) * NC;
        f32x4 c0a = *(const f32x4*)(cp0);
        f32x4 c0b = *(const f32x4*)(cp0 + 4);
        f32x4 c1a = *(const f32x4*)(cp0 + 16 * NC);
        f32x4 c1b = *(const f32x4*)(cp0 + 16 * NC + 4);
        float ss0 = spline_scale[i * OUT_D + bn + lr] * inv256;
        float ss1 = spline_scale[i * OUT_D + bn + 16 + lr] * inv256;
        float rsf = resid_scale[i] * r1;

        uint4 b0, b1;
        b0.x = pack2(ss0 * c0a[0], __builtin_fmaf(ss0, c0a[1], rsf));
        b0.y = pack2(ss0 * c0a[2], ss0 * c0a[3]);
        b0.z = pack2(ss0 * c0b[0], ss0 * c0b[1]);
        b0.w = pack2(ss0 * c0b[2], ss0 * c0b[3]);
        b1.x = pack2(ss1 * c1a[0], __builtin_fmaf(ss1, c1a[1], rsf));
        b1.y = pack2(ss1 * c1a[2], ss1 * c1a[3]);
        b1.z = pack2(ss1 * c1b[0], ss1 * c1b[1]);
        b1.w = pack2(ss1 * c1b[2], ss1 * c1b[3]);

        // A fragments: P_c recurrence in-register; t for f=0..3 = ONE b128
        f32x4 tv = *(const f32x4*)(tb + (size_t)i * TS);
        s16x8 af[4];
        #pragma unroll
        for (int f = 0; f < 4; f++) {
            float t = tv[f];
            float P[8];
            P[0] = 1.0f;
            P[1] = __builtin_fmaf(h, t - 1.0f, h);   // = rnd(h*t)
            #pragma unroll
            for (int n = 2; n < 8; n++)
                P[n] = __builtin_fmaf(bc[n], t * P[n - 1], -(cc[n] * P[n - 2]));
            uint4 pk;
            pk.x = pack2(P[0], P[1]);
            pk.y = pack2(P[2], P[3]);
            pk.z = pack2(P[4], P[5]);
            pk.w = pack2(P[6], P[7]);
            af[f] = *(s16x8*)&pk;
        }

        #pragma unroll
        for (int f = 0; f < 4; f++) {
            acc[f][0] = __builtin_amdgcn_mfma_f32_16x16x32_bf16(af[f], *(s16x8*)&b0, acc[f][0], 0, 0, 0);
            acc[f][1] = __builtin_amdgcn_mfma_f32_16x16x32_bf16(af[f], *(s16x8*)&b1, acc[f][1], 0, 0, 0);
        }
    }

    // ---- Phase 3: K-split reduction (reuse t-panel LDS) ----------------
    __syncthreads();                      // all waves done reading tpanel
    if (kg > 0) {
        float* dst = smem + (mh * 3 + kg - 1) * (64 * 36) + lane * 36;
        #pragma unroll
        for (int f = 0; f < 4; f++)
            #pragma unroll
            for (int g = 0; g < 2; g++)
                *(f32x4*)(dst + f * 8 + g * 4) = acc[f][g];
    }
    __syncthreads();
    if (kg == 0) {
        #pragma unroll
        for (int r = 0; r < 3; r++) {
            const float* src = smem + (mh * 3 + r) * (64 * 36) + lane * 36;
            #pragma unroll
            for (int f = 0; f < 4; f++)
                #pragma unroll
                for (int g = 0; g < 2; g++)
                    acc[f][g] += *(const f32x4*)(src + f * 8 + g * 4);
        }
        // C/D layout: col = lane&15, row = (lane>>4)*4 + j
        #pragma unroll
        for (int f = 0; f < 4; f++)
            #pragma unroll
            for (int g = 0; g < 2; g++)
                #pragma unroll
                for (int j = 0; j < 4; j++) {
                    int r = bm + mh * 64 + f * 16 + il * 4 + j;
                    int c = bn + g * 16 + lr;
                    out[(size_t)r * OUT_D + c] = acc[f][g][j];
                }
    }
}

extern "C" void kernel_launch(void* const* d_in, const int* in_sizes, int n_in,
                              void* d_out, int out_size, void* d_ws, size_t ws_size,
                              hipStream_t stream) {
    const float* x     = (const float*)d_in[0];
    const float* coefs = (const float*)d_in[1];
    const float* alpha = (const float*)d_in[2];
    const float* rs    = (const float*)d_in[3];
    const float* ss    = (const float*)d_in[4];
    float* out = (float*)d_out;

    kan_one<<<dim3((B_SZ / BM) * (OUT_D / BN)), dim3(512), 0, stream>>>(
        x, coefs, alpha, rs, ss, out);
}